// Round 5
// baseline (58.118 us; speedup 1.0000x reference)
//
#include <hip/hip_runtime.h>

#define NV    6890
#define NB    64
#define NCOL  192            // NB * 3 output columns per row
#define NC4   48             // NCOL/4 float4s per Xt row
#define MAIN4 1722           // aligned float4 count per row ( (NV-2)/4 )
#define NITP  28             // scan iterations, padded to multiple of 4
#define VCAP  640            // per-wave LDS (val,col) capacity
#define SCALE (1.0f / (64.0f * 6890.0f))

// ---------------------------------------------------------------------------
// Kernel 1: transpose x[b][w][d] -> Xt[w][b*3+d]; writes coalesced, reads
// L2-absorbed.
// ---------------------------------------------------------------------------
__global__ __launch_bounds__(256) void transpose_x_kernel(
    const float* __restrict__ x, float* __restrict__ Xt) {
  int i = blockIdx.x * blockDim.x + threadIdx.x;
  const int total = NV * NCOL;
  if (i >= total) return;
  int n = i % NCOL;
  int w = i / NCOL;
  Xt[i] = x[(size_t)(n / 3) * (NV * 3) + (size_t)w * 3 + (n % 3)];
}

// ---------------------------------------------------------------------------
// Kernel 2: ONE WAVE per row, two strictly separated phases.
//  Scan: depth-4 prefetch ring; loop body = loads + ballots + ds_write_b64
//        only (saturating store, overflow checked AFTER the loop -> the
//        compiler can keep 4 KB/wave of row loads permanently in flight).
//  Apply: uniform-count loop over the LDS list, unroll x4; gather addresses
//        are acc-independent so 4 Xt-row loads overlap per batch.
// ---------------------------------------------------------------------------
template <bool USE_XT, bool USE_PARTIALS>
__global__ __launch_bounds__(256) void lap_rows_wave_kernel(
    const float* __restrict__ L,
    const float* __restrict__ X,          // Xt if USE_XT, else raw x
    float* __restrict__ partials,
    float* __restrict__ out_atomic) {
  const int lane = threadIdx.x & 63;
  const int wv   = threadIdx.x >> 6;
  const int v    = blockIdx.x * 4 + wv;
  if (v >= NV) return;                    // whole-wave exit; no barriers

  __shared__ float2 s_ent[4][VCAP];
  float2* __restrict__ se = s_ent[wv];

  const float* __restrict__ row = L + (size_t)v * NV;
  const int head     = (v & 1) ? 2 : 0;          // odd rows: 8B-misaligned start
  const int extraPos = head ? 0 : (NV - 2);      // 2 floats outside the f4 body
  const float4* __restrict__ m4 = (const float4*)(row + head);
  const unsigned long long lmask = (1ull << lane) - 1ull;

  // Fallback (non-transposed) per-lane gather offsets: col n -> b=n/3, d=n%3.
  const int n0 = lane, n1 = lane + 64, n2 = lane + 128;
  const size_t o0 = (size_t)(n0 / 3) * (NV * 3) + (n0 % 3);
  const size_t o1 = (size_t)(n1 / 3) * (NV * 3) + (n1 % 3);
  const size_t o2 = (size_t)(n2 / 3) * (NV * 3) + (n2 % 3);

  float4 acc = make_float4(0.f, 0.f, 0.f, 0.f);

  auto gather = [&](float val, int col) {        // one (val,col) contribution
    if (USE_XT) {
      if (lane < NC4) {
        const float4 g = ((const float4*)X)[(size_t)col * NC4 + lane];
        acc.x = fmaf(val, g.x, acc.x);
        acc.y = fmaf(val, g.y, acc.y);
        acc.z = fmaf(val, g.z, acc.z);
        acc.w = fmaf(val, g.w, acc.w);
      }
    } else {
      const size_t cb = (size_t)col * 3;
      acc.x = fmaf(val, X[cb + o0], acc.x);
      acc.y = fmaf(val, X[cb + o1], acc.y);
      acc.z = fmaf(val, X[cb + o2], acc.z);
    }
  };

  int nnz = 0;                                   // wave-uniform
  auto push = [&](bool nz, float val, int col) { // saturating list append
    unsigned long long m = __ballot(nz);
    int pos = nnz + __popcll(m & lmask);
    if (nz && pos < VCAP) se[pos] = make_float2(val, __int_as_float(col));
    nnz += __popcll(m);                          // keeps counting past VCAP
  };

  // ---- Phase 1: scan -------------------------------------------------------
  float4 buf[4];
  #pragma unroll
  for (int k = 0; k < 4; ++k) buf[k] = m4[k * 64 + lane];   // idx <= 255, valid

  {  // 2-float head (odd rows) / tail (even rows); overlaps ring prologue
    const bool act = lane < 2;
    const float val = act ? row[extraPos + lane] : 0.f;
    push(act && val != 0.f, val, extraPos + lane);
  }

  #pragma unroll 4
  for (int it = 0; it < NITP; ++it) {
    const float4 f = buf[it & 3];
    const int i = it * 64 + lane;
    buf[it & 3] = m4[min((it + 4) * 64 + lane, MAIN4 - 1)]; // refill slot early
    const bool act = i < MAIN4;
    const int cb = head + i * 4;
    push(act && f.x != 0.f, f.x, cb);
    push(act && f.y != 0.f, f.y, cb + 1);
    push(act && f.z != 0.f, f.z, cb + 2);
    push(act && f.w != 0.f, f.w, cb + 3);
  }

  // ---- Phase 2: apply ------------------------------------------------------
  if (nnz <= VCAP) {
    const int cnt = nnz;
    #pragma unroll 4
    for (int j = 0; j < cnt; ++j) {              // uniform j: LDS broadcast
      const float2 e = se[j];
      gather(e.x, __float_as_int(e.y));
    }
  } else {
    // Pathological row (never for this input): deterministic slow re-scan.
    acc = make_float4(0.f, 0.f, 0.f, 0.f);
    auto walk = [&](unsigned long long m, float src, int col0, int stride) {
      while (m) {
        const int s = (int)__builtin_ctzll(m);
        m &= m - 1;
        const float val =
            __int_as_float(__builtin_amdgcn_readlane(__float_as_int(src), s));
        gather(val, col0 + s * stride);
      }
    };
    {
      const bool act = lane < 2;
      const float val = act ? row[extraPos + lane] : 0.f;
      walk(__ballot(act && val != 0.f), val, extraPos, 1);
    }
    for (int it = 0; it < 27; ++it) {
      const int i = it * 64 + lane;
      const bool act = i < MAIN4;
      float4 f = make_float4(0.f, 0.f, 0.f, 0.f);
      if (act) f = m4[i];
      const int cb = head + it * 256;
      walk(__ballot(act && f.x != 0.f), f.x, cb + 0, 4);
      walk(__ballot(act && f.y != 0.f), f.y, cb + 1, 4);
      walk(__ballot(act && f.z != 0.f), f.z, cb + 2, 4);
      walk(__ballot(act && f.w != 0.f), f.w, cb + 3, 4);
    }
  }

  // ---- Row contribution ----------------------------------------------------
  float sq = fmaf(acc.x, acc.x,
             fmaf(acc.y, acc.y,
             fmaf(acc.z, acc.z, acc.w * acc.w)));
  #pragma unroll
  for (int o = 32; o > 0; o >>= 1) sq += __shfl_down(sq, o);
  if (lane == 0) {
    if (USE_PARTIALS) partials[v] = sq;
    else              atomicAdd(out_atomic, sq * SCALE);
  }
}

// ---------------------------------------------------------------------------
// Kernel 3: deterministic fixed-order reduction of the 6890 row partials.
// ---------------------------------------------------------------------------
__global__ __launch_bounds__(256) void reduce_kernel(
    const float* __restrict__ p, float* __restrict__ out) {
  int tid = threadIdx.x;
  float a = 0.0f;
  for (int i = tid; i < NV; i += 256) a += p[i];
  #pragma unroll
  for (int o = 32; o > 0; o >>= 1) a += __shfl_down(a, o);
  __shared__ float s_w[4];
  if ((tid & 63) == 0) s_w[tid >> 6] = a;
  __syncthreads();
  if (tid == 0) out[0] = (s_w[0] + s_w[1] + s_w[2] + s_w[3]) * SCALE;
}

__global__ void zero_out_kernel(float* p) {
  if (threadIdx.x == 0 && blockIdx.x == 0) p[0] = 0.0f;
}

// ---------------------------------------------------------------------------
extern "C" void kernel_launch(void* const* d_in, const int* in_sizes, int n_in,
                              void* d_out, int out_size, void* d_ws, size_t ws_size,
                              hipStream_t stream) {
  const float* x = (const float*)d_in[0];   // [64, 6890, 3] f32
  const float* L = (const float*)d_in[1];   // [6890, 6890] f32
  float* out = (float*)d_out;               // scalar f32

  const size_t xt_bytes   = (size_t)NV * NCOL * sizeof(float);  // ~5.3 MB
  const size_t part_bytes = (size_t)NV * sizeof(float);         // ~27.5 KB
  const int grid = (NV + 3) / 4;

  if (ws_size >= xt_bytes + part_bytes) {
    float* Xt       = (float*)d_ws;
    float* partials = (float*)((char*)d_ws + xt_bytes);
    const int total = NV * NCOL;
    transpose_x_kernel<<<(total + 255) / 256, 256, 0, stream>>>(x, Xt);
    lap_rows_wave_kernel<true, true><<<grid, 256, 0, stream>>>(L, Xt, partials, nullptr);
    reduce_kernel<<<1, 256, 0, stream>>>(partials, out);
  } else if (ws_size >= part_bytes) {
    float* partials = (float*)d_ws;
    lap_rows_wave_kernel<false, true><<<grid, 256, 0, stream>>>(L, x, partials, nullptr);
    reduce_kernel<<<1, 256, 0, stream>>>(partials, out);
  } else {
    zero_out_kernel<<<1, 64, 0, stream>>>(out);
    lap_rows_wave_kernel<false, false><<<grid, 256, 0, stream>>>(L, x, nullptr, out);
  }
}